// Round 7
// baseline (313.133 us; speedup 1.0000x reference)
//
#include <hip/hip_runtime.h>
#include <hip/hip_bf16.h>

#define BATCH 8
#define CGUID 3
#define CFEAT 128
#define IMH 224
#define IMW 224
#define NPTS 2048
#define HWSZ (IMH * IMW)

#define TILES 16          // NPTS / 128
#define NPAIR 136         // TILES*(TILES+1)/2
#define BM 128
#define BK 64
#define LDT 72            // padded LDS row stride in bf16 elems

typedef __attribute__((ext_vector_type(8))) short bf16x8;
typedef __attribute__((ext_vector_type(4))) float f32x4;

__device__ __forceinline__ ushort f2bf(float f) {
  unsigned x = __float_as_uint(f);
  unsigned r = (x + 0x7fffu + ((x >> 16) & 1u)) >> 16;   // round-to-nearest-even
  return (ushort)r;
}
__device__ __forceinline__ float bf2f(ushort u) {
  return __uint_as_float(((unsigned)u) << 16);
}

// ---------------------------------------------------------------------------
// Kernel 0: counting-sort points by y (permutation-invariant loss -> never
// undo). Emits slin (sorted linear idx), sc2 (sorted normalized coords),
// zeroes sq and out.
// ---------------------------------------------------------------------------
__global__ __launch_bounds__(256) void sort_kernel(
    const int* __restrict__ coords,
    int* __restrict__ slin, float2* __restrict__ sc2,
    float* __restrict__ sq, float* __restrict__ out)
{
  __shared__ int ys[NPTS], xs[NPTS];
  __shared__ int hist[IMH], offs[IMH];
  int t = threadIdx.x;
  for (int i = t; i < IMH; i += 256) hist[i] = 0;
  __syncthreads();
  for (int i = t; i < NPTS; i += 256) {
    int y = coords[i], x = coords[NPTS + i];
    ys[i] = y; xs[i] = x;
    atomicAdd(&hist[y], 1);
  }
  __syncthreads();
  if (t == 0) {
    int run = 0;
    for (int i = 0; i < IMH; ++i) { offs[i] = run; run += hist[i]; }
  }
  __syncthreads();
  for (int i = t; i < NPTS; i += 256) {
    int y = ys[i], x = xs[i];
    int r = atomicAdd(&offs[y], 1);
    slin[r] = y * IMW + x;
    sc2[r] = make_float2((float)y / 224.0f, (float)x / 224.0f);
  }
  for (int i = t; i < BATCH * NPTS; i += 256) sq[i] = 0.0f;
  if (t == 0) out[0] = 0.0f;
}

// ---------------------------------------------------------------------------
// Kernel 1: gather in sorted order, lane=point. Each wave reads 64 values
// within a ~25KB window of one (b,c) plane (quasi-sequential DRAM order),
// writes selT[b][c][p] coalesced. Also accumulates bf16-rounded sq-norms
// and (cg==0) gathers the 3 guidance channels.
// ---------------------------------------------------------------------------
__global__ __launch_bounds__(256) void gather_kernel(
    const float* __restrict__ features, const float* __restrict__ guidance,
    const int* __restrict__ slin,
    ushort* __restrict__ selT, float4* __restrict__ gxyz, float* __restrict__ sq)
{
  int blk = blockIdx.x;
  int cg = blk & 7, pg = (blk >> 3) & 7, b = blk >> 6;
  int t = threadIdx.x;
  int p = pg * 256 + t;
  int lin = slin[p];
  const float* fb = features + (size_t)b * CFEAT * HWSZ + lin;
  float s = 0.0f;
  #pragma unroll
  for (int i = 0; i < 16; ++i) {
    int c = cg * 16 + i;
    float v = fb[(size_t)c * HWSZ];
    ushort u = f2bf(v);
    float fv = bf2f(u);
    s += fv * fv;
    selT[((size_t)(b * CFEAT + c)) * NPTS + p] = u;
  }
  atomicAdd(&sq[b * NPTS + p], s);
  if (cg == 0) {
    const float* gb = guidance + (size_t)b * CGUID * HWSZ + lin;
    gxyz[b * NPTS + p] = make_float4(gb[0], gb[HWSZ], gb[2 * HWSZ], 0.0f);
  }
}

// ---------------------------------------------------------------------------
// Kernel 2: transpose selT[b][c][n] -> selF[b][n][c] via LDS tiles (64n x 128c).
// ---------------------------------------------------------------------------
__global__ __launch_bounds__(256) void transpose_kernel(
    const ushort* __restrict__ selT, ushort* __restrict__ selF)
{
  __shared__ ushort Ls[CFEAT][LDT];
  int blk = blockIdx.x;
  int b = blk >> 5, nt = blk & 31;
  int nb = nt * 64;
  int t = threadIdx.x;
  #pragma unroll
  for (int pass = 0; pass < 4; ++pass) {
    int idx = pass * 256 + t;
    int c = idx >> 3, q = idx & 7;
    int4 v = *(const int4*)(selT + ((size_t)(b * CFEAT + c)) * NPTS + nb + q * 8);
    *(int4*)(&Ls[c][q * 8]) = v;
  }
  __syncthreads();
  #pragma unroll
  for (int pass = 0; pass < 4; ++pass) {
    int idx = pass * 256 + t;
    int n = idx >> 4, q = idx & 15;
    unsigned w0 = (unsigned)Ls[q * 8 + 0][n] | ((unsigned)Ls[q * 8 + 1][n] << 16);
    unsigned w1 = (unsigned)Ls[q * 8 + 2][n] | ((unsigned)Ls[q * 8 + 3][n] << 16);
    unsigned w2 = (unsigned)Ls[q * 8 + 4][n] | ((unsigned)Ls[q * 8 + 5][n] << 16);
    unsigned w3 = (unsigned)Ls[q * 8 + 6][n] | ((unsigned)Ls[q * 8 + 7][n] << 16);
    int4 o; o.x = (int)w0; o.y = (int)w1; o.z = (int)w2; o.w = (int)w3;
    *(int4*)(selF + ((size_t)(b * NPTS + nb + n)) * CFEAT + q * 8) = o;
  }
}

// ---------------------------------------------------------------------------
// Kernel 3: per (b, tile-pair ti<=tj): 128x128 Gram block via MFMA, fused
// sim-kernel epilogue, block partial sum -> atomicAdd (off-diag doubled).
// ---------------------------------------------------------------------------
__global__ __launch_bounds__(256) void crf_kernel(
    const ushort* __restrict__ selF, const float4* __restrict__ gxyz,
    const float* __restrict__ sq, const float2* __restrict__ sc2,
    float* __restrict__ out)
{
  __shared__ ushort As[BM * LDT];
  __shared__ ushort Bs[BM * LDT];
  __shared__ float4 egN[BM], egM[BM];
  __shared__ float2 ecN[BM], ecM[BM];
  __shared__ float sqN[BM], sqM[BM];
  __shared__ float red[4];

  int b = blockIdx.x / NPAIR;
  int p = blockIdx.x % NPAIR;
  int ti = 0, rem = p;
  while (rem >= TILES - ti) { rem -= TILES - ti; ++ti; }
  int tj = ti + rem;
  int nb0 = ti * BM, mb0 = tj * BM;

  int t = threadIdx.x;
  int lane = t & 63, wid = t >> 6;
  int wr = wid >> 1, wc = wid & 1;              // 2x2 waves -> 64x64 each

  if (t < BM) {
    egN[t] = gxyz[b * NPTS + nb0 + t];
    sqN[t] = sq[b * NPTS + nb0 + t];
    ecN[t] = sc2[nb0 + t];
  } else {
    int q = t - BM;
    egM[q] = gxyz[b * NPTS + mb0 + q];
    sqM[q] = sq[b * NPTS + mb0 + q];
    ecM[q] = sc2[mb0 + q];
  }

  f32x4 acc[4][4];
  #pragma unroll
  for (int i = 0; i < 4; ++i)
    #pragma unroll
    for (int j = 0; j < 4; ++j) acc[i][j] = (f32x4)0.f;

  const ushort* SA = selF + ((size_t)b * NPTS + nb0) * CFEAT;
  const ushort* SB = selF + ((size_t)b * NPTS + mb0) * CFEAT;

  for (int kk = 0; kk < 2; ++kk) {
    __syncthreads();
    #pragma unroll
    for (int pass = 0; pass < 4; ++pass) {
      int idx = t + pass * 256;
      int row = idx >> 3, q = idx & 7;
      int4 va = *(const int4*)(SA + (size_t)row * CFEAT + kk * BK + q * 8);
      *(int4*)(&As[row * LDT + q * 8]) = va;
      int4 vb = *(const int4*)(SB + (size_t)row * CFEAT + kk * BK + q * 8);
      *(int4*)(&Bs[row * LDT + q * 8]) = vb;
    }
    __syncthreads();
    #pragma unroll
    for (int k2 = 0; k2 < 2; ++k2) {
      int kb = k2 * 32 + (lane >> 4) * 8;
      bf16x8 a[4], bv[4];
      #pragma unroll
      for (int i = 0; i < 4; ++i)
        a[i] = *(const bf16x8*)(&As[(wr * 64 + i * 16 + (lane & 15)) * LDT + kb]);
      #pragma unroll
      for (int j = 0; j < 4; ++j)
        bv[j] = *(const bf16x8*)(&Bs[(wc * 64 + j * 16 + (lane & 15)) * LDT + kb]);
      #pragma unroll
      for (int i = 0; i < 4; ++i)
        #pragma unroll
        for (int j = 0; j < 4; ++j)
          acc[i][j] = __builtin_amdgcn_mfma_f32_16x16x32_bf16(a[i], bv[j], acc[i][j], 0, 0, 0);
    }
  }

  // epilogue: C/D layout col=lane&15, row=(lane>>4)*4+r
  float sum = 0.f;
  int mlo = lane & 15, nhi = lane >> 4;
  #pragma unroll
  for (int i = 0; i < 4; ++i) {
    #pragma unroll
    for (int r = 0; r < 4; ++r) {
      int n = wr * 64 + i * 16 + nhi * 4 + r;
      float4 gn = egN[n];
      float2 cn = ecN[n];
      float sn = sqN[n];
      #pragma unroll
      for (int j = 0; j < 4; ++j) {
        int m = wc * 64 + j * 16 + mlo;
        float4 gm = egM[m];
        float2 cm = ecM[m];
        float df = sn + sqM[m] - 2.0f * acc[i][j][r];
        df = fmaxf(df, 0.0f);
        float d0 = gn.x - gm.x, d1 = gn.y - gm.y, d2 = gn.z - gm.z;
        float dg = d0 * d0 + d1 * d1 + d2 * d2;
        float dy = cn.x - cm.x, dx = cn.y - cm.y;
        float dc = dy * dy + dx * dx;
        float sim = 10.0f * __expf(-5.0f * dc - 3.3333333f * dg)
                  +  3.0f * __expf(-100.0f * dc);
        sum += df * sim;
      }
    }
  }

  #pragma unroll
  for (int o = 32; o > 0; o >>= 1) sum += __shfl_down(sum, o);
  if (lane == 0) red[wid] = sum;
  __syncthreads();
  if (t == 0) {
    float tot = red[0] + red[1] + red[2] + red[3];
    float factor = (ti == tj ? 1.0f : 2.0f) * (1.0f / (8.0f * 2048.0f * 2048.0f));
    atomicAdd(out, tot * factor);
  }
}

extern "C" void kernel_launch(void* const* d_in, const int* in_sizes, int n_in,
                              void* d_out, int out_size, void* d_ws, size_t ws_size,
                              hipStream_t stream) {
  const float* guidance = (const float*)d_in[0];
  const float* features = (const float*)d_in[1];
  const int*   coords   = (const int*)d_in[2];
  float* out = (float*)d_out;

  char* ws = (char*)d_ws;
  size_t off = 0;
  ushort* selT = (ushort*)(ws + off); off += (size_t)BATCH * CFEAT * NPTS * 2;  // 4 MiB
  ushort* selF = (ushort*)(ws + off); off += (size_t)BATCH * NPTS * CFEAT * 2;  // 4 MiB
  float4* gxyz = (float4*)(ws + off); off += (size_t)BATCH * NPTS * 16;         // 256 KiB
  float*  sqv  = (float*) (ws + off); off += (size_t)BATCH * NPTS * 4;          // 64 KiB
  float2* sc2  = (float2*)(ws + off); off += (size_t)NPTS * 8;                  // 16 KiB
  int*    slin = (int*)   (ws + off); off += (size_t)NPTS * 4;                  // 8 KiB

  sort_kernel<<<1, 256, 0, stream>>>(coords, slin, sc2, sqv, out);
  gather_kernel<<<BATCH * 8 * 8, 256, 0, stream>>>(features, guidance, slin,
                                                   selT, gxyz, sqv);
  transpose_kernel<<<BATCH * 32, 256, 0, stream>>>(selT, selF);
  crf_kernel<<<BATCH * NPAIR, 256, 0, stream>>>(selF, gxyz, sqv, sc2, out);
}

// Round 11
// 301.724 us; speedup vs baseline: 1.0378x; 1.0378x over previous
//
#include <hip/hip_runtime.h>
#include <hip/hip_bf16.h>

#define BATCH 8
#define CGUID 3
#define CFEAT 128
#define IMH 224
#define IMW 224
#define NPTS 2048
#define HWSZ (IMH * IMW)

#define TILES 16          // NPTS / 128
#define NPAIR 136         // TILES*(TILES+1)/2
#define BM 128
#define BK 64
#define LDT 72            // padded LDS row stride in bf16 elems

typedef __attribute__((ext_vector_type(8))) short bf16x8;
typedef __attribute__((ext_vector_type(4))) float f32x4;

__device__ __forceinline__ ushort f2bf(float f) {
  unsigned x = __float_as_uint(f);
  unsigned r = (x + 0x7fffu + ((x >> 16) & 1u)) >> 16;   // round-to-nearest-even
  return (ushort)r;
}
__device__ __forceinline__ float bf2f(ushort u) {
  return __uint_as_float(((unsigned)u) << 16);
}

// ---------------------------------------------------------------------------
// Kernel 1: gather features/guidance at sampled coords (features are
// L3-resident -> random line-gather is as fast as sorted; R1==R7 evidence).
// One wave per point, lane = channel (and channel+64): coalesced selF writes,
// shuffle-reduced bf16-rounded sq-norm packed into g4.w. Zeroes out[0].
// ---------------------------------------------------------------------------
__global__ __launch_bounds__(256) void gather_kernel(
    const float* __restrict__ guidance, const float* __restrict__ features,
    const int* __restrict__ coords,
    ushort* __restrict__ selF, float4* __restrict__ g4, float* __restrict__ out)
{
  if (blockIdx.x == 0 && threadIdx.x == 0) out[0] = 0.0f;

  int wid  = threadIdx.x >> 6;
  int lane = threadIdx.x & 63;
  int pid  = blockIdx.x * 4 + wid;        // 0 .. B*NPTS-1
  int b = pid >> 11;
  int n = pid & (NPTS - 1);

  int y = coords[n];
  int x = coords[NPTS + n];

  size_t fbase = ((size_t)b * CFEAT) * HWSZ + (size_t)y * IMW + x;
  float f0 = features[fbase + (size_t)lane * HWSZ];
  float f1 = features[fbase + (size_t)(lane + 64) * HWSZ];

  ushort u0 = f2bf(f0), u1 = f2bf(f1);
  size_t so = (size_t)pid * CFEAT;
  selF[so + lane]      = u0;
  selF[so + 64 + lane] = u1;

  // sq-norm of the *rounded* values (keeps diagonal ~exactly 0)
  float ff0 = bf2f(u0), ff1 = bf2f(u1);
  float s = ff0 * ff0 + ff1 * ff1;
  #pragma unroll
  for (int o = 32; o > 0; o >>= 1) s += __shfl_down(s, o);

  float gc = 0.f;
  if (lane < CGUID)
    gc = guidance[((size_t)b * CGUID + lane) * HWSZ + (size_t)y * IMW + x];
  float g0 = __shfl(gc, 0), g1 = __shfl(gc, 1), g2 = __shfl(gc, 2);

  if (lane == 0)
    g4[pid] = make_float4(g0, g1, g2, s);
}

// ---------------------------------------------------------------------------
// Kernel 2: per (b, tile-pair ti<=tj): 128x128 Gram block via MFMA, fused
// sim-kernel epilogue, block partial sum -> atomicAdd (off-diag doubled).
// Normalized coords computed inline from the raw coords input.
// ---------------------------------------------------------------------------
__global__ __launch_bounds__(256) void crf_kernel(
    const ushort* __restrict__ selF, const float4* __restrict__ g4,
    const int* __restrict__ coords, float* __restrict__ out)
{
  __shared__ ushort As[BM * LDT];
  __shared__ ushort Bs[BM * LDT];
  __shared__ float4 egN[BM], egM[BM];
  __shared__ float2 ecN[BM], ecM[BM];
  __shared__ float red[4];

  int b = blockIdx.x / NPAIR;
  int p = blockIdx.x % NPAIR;
  int ti = 0, rem = p;
  while (rem >= TILES - ti) { rem -= TILES - ti; ++ti; }
  int tj = ti + rem;
  int nb0 = ti * BM, mb0 = tj * BM;

  int t = threadIdx.x;
  int lane = t & 63, wid = t >> 6;
  int wr = wid >> 1, wc = wid & 1;              // 2x2 waves -> 64x64 each

  // stage epilogue side-data (coords normalized inline)
  if (t < BM) {
    egN[t] = g4[b * NPTS + nb0 + t];
    ecN[t] = make_float2((float)coords[nb0 + t] / 224.0f,
                         (float)coords[NPTS + nb0 + t] / 224.0f);
  } else {
    int q = t - BM;
    egM[q] = g4[b * NPTS + mb0 + q];
    ecM[q] = make_float2((float)coords[mb0 + q] / 224.0f,
                         (float)coords[NPTS + mb0 + q] / 224.0f);
  }

  f32x4 acc[4][4];
  #pragma unroll
  for (int i = 0; i < 4; ++i)
    #pragma unroll
    for (int j = 0; j < 4; ++j) acc[i][j] = (f32x4)0.f;

  const ushort* SA = selF + ((size_t)b * NPTS + nb0) * CFEAT;
  const ushort* SB = selF + ((size_t)b * NPTS + mb0) * CFEAT;

  for (int kk = 0; kk < 2; ++kk) {
    __syncthreads();
    #pragma unroll
    for (int pass = 0; pass < 4; ++pass) {
      int idx = t + pass * 256;
      int row = idx >> 3, q = idx & 7;          // 8 int4 per 64-elem row-half
      int4 va = *(const int4*)(SA + (size_t)row * CFEAT + kk * BK + q * 8);
      *(int4*)(&As[row * LDT + q * 8]) = va;
      int4 vb = *(const int4*)(SB + (size_t)row * CFEAT + kk * BK + q * 8);
      *(int4*)(&Bs[row * LDT + q * 8]) = vb;
    }
    __syncthreads();
    #pragma unroll
    for (int k2 = 0; k2 < 2; ++k2) {
      int kb = k2 * 32 + (lane >> 4) * 8;       // bf16 offset within row
      bf16x8 a[4], bv[4];
      #pragma unroll
      for (int i = 0; i < 4; ++i)
        a[i] = *(const bf16x8*)(&As[(wr * 64 + i * 16 + (lane & 15)) * LDT + kb]);
      #pragma unroll
      for (int j = 0; j < 4; ++j)
        bv[j] = *(const bf16x8*)(&Bs[(wc * 64 + j * 16 + (lane & 15)) * LDT + kb]);
      #pragma unroll
      for (int i = 0; i < 4; ++i)
        #pragma unroll
        for (int j = 0; j < 4; ++j)
          acc[i][j] = __builtin_amdgcn_mfma_f32_16x16x32_bf16(a[i], bv[j], acc[i][j], 0, 0, 0);
    }
  }

  // epilogue: C/D layout col=lane&15, row=(lane>>4)*4+r
  float sum = 0.f;
  int mlo = lane & 15, nhi = lane >> 4;
  #pragma unroll
  for (int i = 0; i < 4; ++i) {
    #pragma unroll
    for (int r = 0; r < 4; ++r) {
      int n = wr * 64 + i * 16 + nhi * 4 + r;
      float4 gn = egN[n];
      float2 cn = ecN[n];
      #pragma unroll
      for (int j = 0; j < 4; ++j) {
        int m = wc * 64 + j * 16 + mlo;
        float4 gm = egM[m];
        float2 cm = ecM[m];
        float df = gn.w + gm.w - 2.0f * acc[i][j][r];
        df = fmaxf(df, 0.0f);
        float d0 = gn.x - gm.x, d1 = gn.y - gm.y, d2 = gn.z - gm.z;
        float dg = d0 * d0 + d1 * d1 + d2 * d2;
        float dy = cn.x - cm.x, dx = cn.y - cm.y;
        float dc = dy * dy + dx * dx;
        float sim = 10.0f * __expf(-5.0f * dc - 3.3333333f * dg)
                  +  3.0f * __expf(-100.0f * dc);
        sum += df * sim;
      }
    }
  }

  #pragma unroll
  for (int o = 32; o > 0; o >>= 1) sum += __shfl_down(sum, o);
  if (lane == 0) red[wid] = sum;
  __syncthreads();
  if (t == 0) {
    float tot = red[0] + red[1] + red[2] + red[3];
    float factor = (ti == tj ? 1.0f : 2.0f) * (1.0f / (8.0f * 2048.0f * 2048.0f));
    atomicAdd(out, tot * factor);
  }
}

extern "C" void kernel_launch(void* const* d_in, const int* in_sizes, int n_in,
                              void* d_out, int out_size, void* d_ws, size_t ws_size,
                              hipStream_t stream) {
  const float* guidance = (const float*)d_in[0];
  const float* features = (const float*)d_in[1];
  const int*   coords   = (const int*)d_in[2];
  float* out = (float*)d_out;

  char* ws = (char*)d_ws;
  ushort* selF = (ushort*)ws;                                        // 4 MiB
  float4* g4   = (float4*)(ws + (size_t)BATCH * NPTS * CFEAT * 2);   // 256 KiB

  gather_kernel<<<BATCH * NPTS / 4, 256, 0, stream>>>(guidance, features, coords,
                                                      selF, g4, out);
  crf_kernel<<<BATCH * NPAIR, 256, 0, stream>>>(selF, g4, coords, out);
}